// Round 1
// baseline (115.859 us; speedup 1.0000x reference)
//
#include <hip/hip_runtime.h>

// ChamferLoss: predicted/target (64, 4096) fp32.
// Point j of batch b = (params[b][j], params[b][2048+j]).
// out = mean_b [ mean_j min_i dist(p_i, t_j) + mean_i min_j dist(p_i, t_j) ]
//     = (1/(64*2048)) * sum over all 262144 (dir, batch, point) sqrt(min d^2).
// Trick: min(sqrt) = sqrt(min) -> sqrt hoisted out of the 268M-pair inner loop.

constexpr int K = 2048;       // points per side per batch
constexpr int BLOCK = 256;    // threads per block (4 waves)

__global__ __launch_bounds__(BLOCK) void chamfer_min_kernel(
    const float* __restrict__ pred, const float* __restrict__ targ,
    float* __restrict__ out) {
  const int tile = blockIdx.x;   // which 256-query-point tile   [0,8)
  const int b    = blockIdx.y;   // batch                        [0,64)
  const int dir  = blockIdx.z;   // 0: query=pred/opp=targ, 1: swapped

  const float* qbase = (dir == 0 ? pred : targ) + (size_t)b * (2 * K);
  const float* obase = (dir == 0 ? targ : pred) + (size_t)b * (2 * K);

  // Stage all 2048 opposite points into LDS as (x,y) pairs. 16 KB.
  __shared__ float4 smem4[K / 2];
  float2* smem2 = reinterpret_cast<float2*>(smem4);
  for (int j = threadIdx.x; j < K; j += BLOCK) {
    smem2[j] = make_float2(obase[j], obase[K + j]);  // coalesced global reads
  }
  __syncthreads();

  // Each thread owns one query point (registers).
  const int qi = tile * BLOCK + threadIdx.x;
  const float px = qbase[qi];
  const float py = qbase[K + qi];

  // Scan all opposite points; 4 independent min accumulators for ILP.
  float m0 = 3.4e38f, m1 = 3.4e38f, m2 = 3.4e38f, m3 = 3.4e38f;
  #pragma unroll 4
  for (int j4 = 0; j4 < K / 2; j4 += 2) {
    const float4 a = smem4[j4];       // points 2*j4, 2*j4+1   (ds_read_b128 broadcast)
    const float4 c = smem4[j4 + 1];   // points 2*j4+2, 2*j4+3
    const float dx0 = px - a.x, dy0 = py - a.y;
    const float dx1 = px - a.z, dy1 = py - a.w;
    const float dx2 = px - c.x, dy2 = py - c.y;
    const float dx3 = px - c.z, dy3 = py - c.w;
    m0 = fminf(m0, dx0 * dx0 + dy0 * dy0);
    m1 = fminf(m1, dx1 * dx1 + dy1 * dy1);
    m2 = fminf(m2, dx2 * dx2 + dy2 * dy2);
    m3 = fminf(m3, dx3 * dx3 + dy3 * dy3);
  }
  const float msq  = fminf(fminf(m0, m1), fminf(m2, m3));
  const float dmin = sqrtf(fmaxf(msq, 0.0f));

  // Wave (64-lane) shuffle reduction, then cross-wave via tiny LDS array.
  float v = dmin;
  #pragma unroll
  for (int off = 32; off > 0; off >>= 1) v += __shfl_down(v, off, 64);

  __shared__ float wsum[BLOCK / 64];
  const int lane = threadIdx.x & 63;
  const int wid  = threadIdx.x >> 6;
  if (lane == 0) wsum[wid] = v;
  __syncthreads();
  if (threadIdx.x == 0) {
    const float s = wsum[0] + wsum[1] + wsum[2] + wsum[3];
    atomicAdd(out, s * (1.0f / (64.0f * 2048.0f)));
  }
}

extern "C" void kernel_launch(void* const* d_in, const int* in_sizes, int n_in,
                              void* d_out, int out_size, void* d_ws, size_t ws_size,
                              hipStream_t stream) {
  const float* pred = (const float*)d_in[0];
  const float* targ = (const float*)d_in[1];
  float* out = (float*)d_out;

  // Harness poisons d_out with 0xAA before every timed replay — zero it.
  hipMemsetAsync(out, 0, sizeof(float), stream);

  dim3 grid(K / BLOCK, 64, 2);  // 8 tiles x 64 batches x 2 directions = 1024 blocks
  chamfer_min_kernel<<<grid, dim3(BLOCK), 0, stream>>>(pred, targ, out);
}